// Round 11
// baseline (282.935 us; speedup 1.0000x reference)
//
#include <hip/hip_runtime.h>

#define CLS  64
#define DIM  256
#define NBLK 256         // k_main blocks (1/CU), 4 waves each
#define P2   4           // reduce1 parts per class
#define HB   256         // hist blocks
#define HT   256         // hist threads

typedef float f32x4 __attribute__((ext_vector_type(4)));
typedef short s16x8 __attribute__((ext_vector_type(8)));   // bf16x8 fragment (guide-blessed)

// ---- wave64 sum via DPP (VALU pipe); result uniform across all lanes ----
__device__ __forceinline__ float wave_sum64(float f) {
    int t;
    t = __builtin_amdgcn_update_dpp(0, __float_as_int(f), 0x111, 0xf, 0xf, false); f += __int_as_float(t); // row_shr:1
    t = __builtin_amdgcn_update_dpp(0, __float_as_int(f), 0x112, 0xf, 0xf, false); f += __int_as_float(t); // row_shr:2
    t = __builtin_amdgcn_update_dpp(0, __float_as_int(f), 0x114, 0xf, 0xe, false); f += __int_as_float(t); // row_shr:4
    t = __builtin_amdgcn_update_dpp(0, __float_as_int(f), 0x118, 0xf, 0xc, false); f += __int_as_float(t); // row_shr:8
    t = __builtin_amdgcn_update_dpp(0, __float_as_int(f), 0x142, 0xa, 0xf, false); f += __int_as_float(t); // row_bcast:15
    t = __builtin_amdgcn_update_dpp(0, __float_as_int(f), 0x143, 0xc, 0xf, false); f += __int_as_float(t); // row_bcast:31
    return __int_as_float(__builtin_amdgcn_readlane(__float_as_int(f), 63));
}

// ---- S1: per-block label histogram -> hist[HB][CLS] (also provides counts) ----
__global__ __launch_bounds__(HT) void k_hist(const int* __restrict__ labels, int N,
                                             int* __restrict__ hist)
{
    __shared__ int h[CLS];
    if (threadIdx.x < CLS) h[threadIdx.x] = 0;
    __syncthreads();
    const int chunk = (N + gridDim.x - 1) / gridDim.x;
    const int s = blockIdx.x * chunk;
    const int e = min(N, s + chunk);
    for (int i = s + threadIdx.x; i < e; i += blockDim.x)
        atomicAdd(&h[labels[i]], 1);
    __syncthreads();
    if (threadIdx.x < CLS) hist[blockIdx.x * CLS + threadIdx.x] = h[threadIdx.x];
}

// ---- main: sequential stream; one-hot MFMA accumulate; wave-private, barrier-free ----
__global__ __launch_bounds__(256, 1) void k_main(
    const float* __restrict__ emb, const int* __restrict__ labels, int N,
    float* __restrict__ partials)   // [CLS][NBLK][DIM]
{
    __shared__ float lred[4][16][258];        // epilogue scratch only (~66 KB)

    const int tid  = threadIdx.x;
    const int w    = tid >> 6;
    const int lane = tid & 63;
    const int q    = lane >> 4;               // quarter: owns rows 8q..8q+7 of each K-step
    const int col  = lane & 15;               // A row (class mod 16) / B col (dim mod 16)
    const int b    = blockIdx.x;

    // accumulators: tile (mt,nt) holds sums[mt*16 + q*4 + r][nt*16 + col]
    f32x4 acc[4][16];
    #pragma unroll
    for (int mt = 0; mt < 4; ++mt)
        #pragma unroll
        for (int nt = 0; nt < 16; ++nt) acc[mt][nt] = (f32x4){0.f, 0.f, 0.f, 0.f};

    const long long gw   = (long long)b * 4 + w;                       // global wave id
    const long long span = (((long long)N + 1023) / 1024 + 31) & ~31LL; // rows per wave, mult of 32
    long long base = gw * span;
    const long long bend = (base + span < (long long)N) ? base + span : (long long)N;

    for (; base < bend; base += 32) {
        // ---- phase 1: row norms (sequential dwordx4 stream; rows base..base+31) ----
        float myinv[8] = {0,0,0,0,0,0,0,0};   // inv-norms of MY quarter's 8 rows
        #pragma unroll
        for (int g = 0; g < 4; ++g) {
            #pragma unroll
            for (int j = 0; j < 8; ++j) {
                const long long r = base + g * 8 + j;
                f32x4 v = {0.f, 0.f, 0.f, 0.f};
                if (r < N) v = *(reinterpret_cast<const f32x4*>(emb + (size_t)r * DIM) + lane);
                const float ss  = wave_sum64(v.x*v.x + v.y*v.y + v.z*v.z + v.w*v.w);
                const float inv = 1.0f / fmaxf(sqrtf(ss), 1e-12f);
                if (q == g) myinv[j] = inv;
            }
        }
        // ---- labels of my quarter's 8 rows -> one-hot A fragments ----
        int lab[8];
        #pragma unroll
        for (int j = 0; j < 8; ++j) {
            const long long r = base + q * 8 + j;
            lab[j] = (r < N) ? labels[r] : -1;
        }
        s16x8 afr[4];
        #pragma unroll
        for (int mt = 0; mt < 4; ++mt) {
            const int c = mt * 16 + col;      // A[row=col][k] for class-tile mt
            #pragma unroll
            for (int j = 0; j < 8; ++j)
                afr[mt][j] = (lab[j] == c) ? (short)0x3F80 : (short)0;   // bf16 1.0 / 0.0
        }
        // ---- phase 2: B fragments (L2-hot scalar re-reads, scaled) + 64 MFMA ----
        #pragma unroll
        for (int nt = 0; nt < 16; ++nt) {
            s16x8 bfr;
            #pragma unroll
            for (int j = 0; j < 8; ++j) {
                const long long r = base + q * 8 + j;
                float x = 0.f;
                if (r < N) x = emb[(size_t)r * DIM + nt * 16 + col];
                x *= myinv[j];
                const unsigned u = __float_as_uint(x);
                bfr[j] = (short)((u + 0x8000u) >> 16);                   // bf16 round
            }
            #pragma unroll
            for (int mt = 0; mt < 4; ++mt)
                acc[mt][nt] = __builtin_amdgcn_mfma_f32_16x16x32_bf16(
                    afr[mt], bfr, acc[mt][nt], 0, 0, 0);
        }
    }

    // ---- epilogue: block-reduce 4 waves via LDS, 16-class chunks ----
    for (int mt = 0; mt < 4; ++mt) {
        #pragma unroll
        for (int nt = 0; nt < 16; ++nt) {
            #pragma unroll
            for (int r = 0; r < 4; ++r)
                lred[w][q * 4 + r][nt * 16 + col] = acc[mt][nt][r];
        }
        __syncthreads();
        for (int rowc = 0; rowc < 16; ++rowc) {
            const int c = mt * 16 + rowc;
            const float s = lred[0][rowc][tid] + lred[1][rowc][tid]
                          + lred[2][rowc][tid] + lred[3][rowc][tid];
            partials[((size_t)c * NBLK + b) * DIM + tid] = s;
        }
        __syncthreads();
    }
}

// ---- reduce1: fold the NBLK block-partials to P2 chunks per class (coalesced) ----
__global__ __launch_bounds__(256) void k_reduce1(
    const float* __restrict__ partials, float* __restrict__ red1)
{
    const int c = blockIdx.x >> 2;             // / P2
    const int p = blockIdx.x & (P2 - 1);
    const int d = threadIdx.x;                 // 256 threads = one dim each
    const float* src = partials + ((size_t)c * NBLK + p * (NBLK / P2)) * DIM + d;
    float s = 0.f;
    #pragma unroll 8
    for (int bb = 0; bb < NBLK / P2; ++bb) s += src[(size_t)bb * DIM];
    red1[((size_t)c * P2 + p) * DIM + d] = s;
}

// ---- per-class loss (counts from hist) ----
__global__ __launch_bounds__(256) void k_classloss(
    const float* __restrict__ red1, const int* __restrict__ hist,
    float* __restrict__ closs, float* __restrict__ cvalid)
{
    const int c = blockIdx.x;   // 64 blocks
    const int d = threadIdx.x;  // 256 threads
    float s = 0.f;
    #pragma unroll
    for (int p = 0; p < P2; ++p) s += red1[((size_t)c * P2 + p) * DIM + d];
    const float w2 = wave_sum64(s * s);
    const float cw = wave_sum64((float)hist[d * CLS + c]);   // HB==256 hist rows
    __shared__ float reds[4], redc[4];
    if ((d & 63) == 0) { reds[d >> 6] = w2; redc[d >> 6] = cw; }
    __syncthreads();
    if (d == 0) {
        float s2   = reds[0] + reds[1] + reds[2] + reds[3];  // ||sums_c||^2
        float cnt  = redc[0] + redc[1] + redc[2] + redc[3];
        float invc = 1.0f / fmaxf(cnt, 1.0f);
        float cn   = sqrtf(s2) * invc;                       // ||center_raw||
        float dot  = s2 * invc / fmaxf(cn, 1e-12f);          // sum over class of sim
        float pcs  = cnt - dot;                              // sum over class of (1 - sim)
        bool valid = cnt > 1.0f;
        closs[c]  = valid ? pcs * invc : 0.0f;
        cvalid[c] = valid ? 1.0f : 0.0f;
    }
}

// ---- final scalar ----
__global__ void k_final(const float* __restrict__ closs, const float* __restrict__ cvalid,
                        const int* __restrict__ epoch, float* __restrict__ out)
{
    const int t = threadIdx.x;  // 64
    const float sl = wave_sum64(closs[t]);
    const float nv = wave_sum64(cvalid[t]);
    if (t == 0) {
        float res = (nv > 0.0f) ? (sl / fmaxf(nv, 1.0f)) : 0.0f;
        if (epoch[0] < 1) res = 0.0f;   // START guard
        out[0] = res;
    }
}

extern "C" void kernel_launch(void* const* d_in, const int* in_sizes, int n_in,
                              void* d_out, int out_size, void* d_ws, size_t ws_size,
                              hipStream_t stream)
{
    const float* emb    = (const float*)d_in[0];
    const int*   labels = (const int*)d_in[1];
    const int*   epoch  = (const int*)d_in[2];
    float*       out    = (float*)d_out;
    const int N = in_sizes[0] / DIM;

    // workspace carve-up (all regions fully written before read, every call)
    char* ws = (char*)d_ws;
    size_t off = 0;
    auto carve = [&](size_t bytes) { size_t o = off; off = (off + bytes + 255) & ~(size_t)255; return o; };
    float* partials = (float*)(ws + carve((size_t)CLS * NBLK * DIM * sizeof(float)));  // 16 MB
    int*   hist     = (int*)  (ws + carve((size_t)HB * CLS * sizeof(int)));            // 64 KB
    float* red1     = (float*)(ws + carve((size_t)CLS * P2 * DIM * sizeof(float)));    // 256 KB
    float* closs    = (float*)(ws + carve((size_t)CLS * sizeof(float)));
    float* cvalid   = (float*)(ws + carve((size_t)CLS * sizeof(float)));
    (void)ws_size;  // ~16.4 MB needed; harness provides ~1 GiB (observed via poison fill)

    k_hist     <<<HB,       HT,  0, stream>>>(labels, N, hist);
    k_main     <<<NBLK,     256, 0, stream>>>(emb, labels, N, partials);
    k_reduce1  <<<CLS * P2, 256, 0, stream>>>(partials, red1);
    k_classloss<<<CLS,      256, 0, stream>>>(red1, hist, closs, cvalid);
    k_final    <<<1,        64,  0, stream>>>(closs, cvalid, epoch, out);
}